// Round 11
// baseline (286.475 us; speedup 1.0000x reference)
//
#include <hip/hip_runtime.h>
#include <stdint.h>

#define D_ 1024
#define S_ 2048
#define B_ 8

typedef _Float16 h16;
typedef _Float16 f16x8 __attribute__((ext_vector_type(8)));
typedef _Float16 f16x4 __attribute__((ext_vector_type(4)));
typedef float    f32x4 __attribute__((ext_vector_type(4)));

typedef __attribute__((address_space(3))) void lds_void;
typedef const __attribute__((address_space(1))) void g_void;

#define MFMA16(a, b, c) __builtin_amdgcn_mfma_f32_16x16x32_f16(a, b, c, 0, 0, 0)
#define VMCNT(n) asm volatile("s_waitcnt vmcnt(" #n ")" ::: "memory")
#define SFENCE() __builtin_amdgcn_sched_barrier(0)
#define SBAR() __builtin_amdgcn_s_barrier()

// Stage one 16-row x 32-half (1KB) chunk via global_load_lds (linear LDS dest).
// Swizzle (both-sides, rule #21): stored slot s' holds logical 16B col-chunk
// c = s' ^ ((row>>1)&3).  Write: lane l -> row=l>>2, slot=l&3, global chunk
// c=(l&3)^((l>>3)&3).  Read: logical chunk g at slot g ^ ((row>>1)&3).
__device__ __forceinline__ void stage16(const h16* g0, int ld, h16* lchunk) {
  int lane = threadIdx.x & 63;
  int c = (lane & 3) ^ ((lane >> 3) & 3);
  const h16* ga = g0 + (size_t)(lane >> 2) * ld + c * 8;
  __builtin_amdgcn_global_load_lds((g_void*)ga, (lds_void*)lchunk, 16, 0, 0);
}

// ---------------- kernel 0: fp16 casts of Wq, Wk ----------------------------
__global__ void k_cast(const float* __restrict__ Wq, const float* __restrict__ Wk,
                       h16* __restrict__ Wqh, h16* __restrict__ Wkh) {
  int i = blockIdx.x * 256 + threadIdx.x;
  const int n4 = (D_ * D_) / 4;
  const float4* src;
  h16* dst;
  if (i < n4) { src = (const float4*)Wq; dst = Wqh; }
  else        { src = (const float4*)Wk; dst = Wkh; i -= n4; }
  float4 a = src[i];
  f16x4 o;
  o[0] = (h16)a.x; o[1] = (h16)a.y; o[2] = (h16)a.z; o[3] = (h16)a.w;
  *(f16x4*)(dst + (size_t)i * 4) = o;
}

// -- kernel 1: u[e]=Wv[e,:]·Wo ; v2[e]=Wk[e,:]·bq ; u[D]=bv·Wo (wave/row) ----
__global__ void k_u(const float* __restrict__ Wv, const float* __restrict__ Wk,
                    const float* __restrict__ Wo, const float* __restrict__ bq_,
                    const float* __restrict__ bv, float* __restrict__ u,
                    float* __restrict__ v2) {
  int lane = threadIdx.x & 63;
  if (blockIdx.x == 256) {            // bias block: u[D] = bv·Wo, one wave
    if (threadIdx.x < 64) {
      float s = 0.f;
      #pragma unroll
      for (int j = 0; j < 4; ++j) {
        float4 a = ((const float4*)bv)[j * 64 + lane];
        float4 b = ((const float4*)Wo)[j * 64 + lane];
        s += a.x * b.x + a.y * b.y + a.z * b.z + a.w * b.w;
      }
      #pragma unroll
      for (int off = 32; off; off >>= 1) s += __shfl_xor(s, off, 64);
      if (lane == 0) u[D_] = s;
    }
    return;
  }
  int row = blockIdx.x * 4 + (threadIdx.x >> 6);
  const float4* rv = (const float4*)(Wv + (size_t)row * D_);
  const float4* rk = (const float4*)(Wk + (size_t)row * D_);
  const float4* w4 = (const float4*)Wo;
  const float4* b4 = (const float4*)bq_;
  float s1 = 0.f, s2 = 0.f;
  #pragma unroll
  for (int j = 0; j < 4; ++j) {
    int c = j * 64 + lane;
    float4 a = rv[c], b = w4[c];
    s1 += a.x * b.x + a.y * b.y + a.z * b.z + a.w * b.w;
    float4 e = rk[c], f = b4[c];
    s2 += e.x * f.x + e.y * f.y + e.z * f.z + e.w * f.w;
  }
  #pragma unroll
  for (int off = 32; off; off >>= 1) {
    s1 += __shfl_xor(s1, off, 64);
    s2 += __shfl_xor(s2, off, 64);
  }
  if (lane == 0) { u[row] = s1; v2[row] = s2; }
}

// - kernel 2: xh=fp16(x); w[r]=x·u+u[D]; c[r]=x·v2  (one wave per row) -------
__global__ void k_xw(const float* __restrict__ x, const float* __restrict__ u,
                     const float* __restrict__ v2, h16* __restrict__ xh,
                     float* __restrict__ w, float* __restrict__ cv) {
  int row = blockIdx.x * 4 + (threadIdx.x >> 6);
  int lane = threadIdx.x & 63;
  const float4* xr = (const float4*)(x + (size_t)row * D_);
  const float4* u4 = (const float4*)u;
  const float4* c4 = (const float4*)v2;
  h16* xo = xh + (size_t)row * D_;
  float s1 = 0.f, s2 = 0.f;
  #pragma unroll
  for (int j = 0; j < 4; ++j) {
    int c = j * 64 + lane;
    float4 a = xr[c];
    float4 b = u4[c];
    float4 e = c4[c];
    s1 += a.x * b.x + a.y * b.y + a.z * b.z + a.w * b.w;
    s2 += a.x * e.x + a.y * e.y + a.z * e.z + a.w * e.w;
    f16x4 o;
    o[0] = (h16)a.x; o[1] = (h16)a.y; o[2] = (h16)a.z; o[3] = (h16)a.w;
    *(f16x4*)(xo + c * 4) = o;
  }
  #pragma unroll
  for (int off = 32; off; off >>= 1) {
    s1 += __shfl_xor(s1, off, 64);
    s2 += __shfl_xor(s2, off, 64);
  }
  if (lane == 0) { w[row] = s1 + u[D_]; cv[row] = s2; }
}

// -- kernel 3: Mt[e][d] = sum_d' Wkh[e][d'] Wqh[d][d']  (128x128 tiles) ------
__global__ __launch_bounds__(256, 4) void k_mt(
    const h16* __restrict__ Wkh, const h16* __restrict__ Wqh,
    h16* __restrict__ Mt) {
  __shared__ alignas(16) h16 As[3][128 * 32];
  __shared__ alignas(16) h16 Bs[3][128 * 32];
  int tid = threadIdx.x;
  int w = tid >> 6, lane = tid & 63;
  int wr = w >> 1, wc = w & 1;
  int g = lane >> 4, l15 = lane & 15;
  int swz = (l15 >> 1) & 3;
  int m0 = (blockIdx.x >> 3) * 128, n0 = (blockIdx.x & 7) * 128;

  const h16* abase0 = Wkh + (size_t)(m0 + (2 * w) * 16) * D_;
  const h16* abase1 = abase0 + (size_t)16 * D_;
  const h16* bbase0 = Wqh + (size_t)(n0 + (2 * w) * 16) * D_;
  const h16* bbase1 = bbase0 + (size_t)16 * D_;

  f32x4 acc[4][4] = {};

  #define STAGE_MT(ap, bp, k)                                \
    {                                                        \
      int k0_ = (k) * 32;                                    \
      stage16(abase0 + k0_, D_, (ap) + (2 * w) * 512);       \
      stage16(abase1 + k0_, D_, (ap) + (2 * w + 1) * 512);   \
      stage16(bbase0 + k0_, D_, (bp) + (2 * w) * 512);       \
      stage16(bbase1 + k0_, D_, (bp) + (2 * w + 1) * 512);   \
    }

  h16 *A0 = As[0], *A1 = As[1], *A2 = As[2];
  h16 *B0 = Bs[0], *B1 = Bs[1], *B2 = Bs[2];
  STAGE_MT(A0, B0, 0);
  STAGE_MT(A1, B1, 1);
  for (int k = 0; k < 32; ++k) {
    if (k + 2 < 32) {
      STAGE_MT(A2, B2, k + 2);
      VMCNT(8);
    } else if (k + 1 < 32) {
      VMCNT(4);
    } else {
      VMCNT(0);
    }
    SFENCE();
    SBAR();
    SFENCE();
    f16x8 af[4], bf[4];
    #pragma unroll
    for (int i = 0; i < 4; ++i) {
      af[i] = *(const f16x8*)(A0 + (wr * 64 + i * 16 + l15) * 32 + (g ^ swz) * 8);
      bf[i] = *(const f16x8*)(B0 + (wc * 64 + i * 16 + l15) * 32 + (g ^ swz) * 8);
    }
    __builtin_amdgcn_s_setprio(1);
    #pragma unroll
    for (int mi = 0; mi < 4; ++mi)
      #pragma unroll
      for (int ni = 0; ni < 4; ++ni)
        acc[mi][ni] = MFMA16(af[mi], bf[ni], acc[mi][ni]);
    __builtin_amdgcn_s_setprio(0);
    SBAR();
    h16* t;
    t = A0; A0 = A1; A1 = A2; A2 = t;
    t = B0; B0 = B1; B1 = B2; B2 = t;
  }

  #pragma unroll
  for (int ni = 0; ni < 4; ++ni) {
    int n = n0 + wc * 64 + ni * 16 + l15;
    #pragma unroll
    for (int mi = 0; mi < 4; ++mi) {
      #pragma unroll
      for (int r = 0; r < 4; ++r) {
        int m = m0 + wr * 64 + mi * 16 + g * 4 + r;
        Mt[(size_t)m * D_ + n] = (h16)(acc[mi][ni][r]);
      }
    }
  }
}

// ------ kernel 4: y[16384][1024] = xh · Mt-rows  (fp16 out) -----------------
// 256x256 tile, 512 thr / 8 waves (2x4), per-wave 128x64 (acc[8][4]).
// 4 stage16/wave/step -> steady VMCNT(8); 3-buffer counted schedule.
// Grid 256 = exactly 1 block/CU.
__global__ __launch_bounds__(512, 2) void k_y(
    const h16* __restrict__ xh, const h16* __restrict__ Mt,
    h16* __restrict__ y) {
  __shared__ alignas(16) h16 As[3][256 * 32];   // 48 KB
  __shared__ alignas(16) h16 Bs[3][256 * 32];   // 48 KB
  int tid = threadIdx.x;
  int w = tid >> 6, lane = tid & 63;
  int wq = w >> 2, wn = w & 3;                   // wave: 128m x 64n sub-tile
  int g = lane >> 4, l15 = lane & 15;
  int swz = (l15 >> 1) & 3;

  int idx = (blockIdx.x & 7) * 32 + (blockIdx.x >> 3);
  int m0 = (idx >> 2) * 256, n0 = (idx & 3) * 256;

  const h16* abase0 = xh + (size_t)(m0 + (2 * w) * 16) * D_;
  const h16* abase1 = abase0 + (size_t)16 * D_;
  const h16* bbase0 = Mt + (size_t)(n0 + (2 * w) * 16) * D_;
  const h16* bbase1 = bbase0 + (size_t)16 * D_;

  f32x4 acc[8][4] = {};

  #define STAGE_Y(ap, bp, k)                                 \
    {                                                        \
      int k0_ = (k) * 32;                                    \
      stage16(abase0 + k0_, D_, (ap) + (2 * w) * 512);       \
      stage16(abase1 + k0_, D_, (ap) + (2 * w + 1) * 512);   \
      stage16(bbase0 + k0_, D_, (bp) + (2 * w) * 512);       \
      stage16(bbase1 + k0_, D_, (bp) + (2 * w + 1) * 512);   \
    }

  h16 *A0 = As[0], *A1 = As[1], *A2 = As[2];
  h16 *B0 = Bs[0], *B1 = Bs[1], *B2 = Bs[2];
  STAGE_Y(A0, B0, 0);
  STAGE_Y(A1, B1, 1);
  for (int k = 0; k < 32; ++k) {
    if (k + 2 < 32) {
      STAGE_Y(A2, B2, k + 2);
      VMCNT(8);
    } else if (k + 1 < 32) {
      VMCNT(4);
    } else {
      VMCNT(0);
    }
    SFENCE();
    SBAR();
    SFENCE();
    f16x8 af[8], bf[4];
    #pragma unroll
    for (int i = 0; i < 8; ++i)
      af[i] = *(const f16x8*)(A0 + (wq * 128 + i * 16 + l15) * 32 + (g ^ swz) * 8);
    #pragma unroll
    for (int i = 0; i < 4; ++i)
      bf[i] = *(const f16x8*)(B0 + (wn * 64 + i * 16 + l15) * 32 + (g ^ swz) * 8);
    __builtin_amdgcn_s_setprio(1);
    #pragma unroll
    for (int mi = 0; mi < 8; ++mi)
      #pragma unroll
      for (int ni = 0; ni < 4; ++ni)
        acc[mi][ni] = MFMA16(af[mi], bf[ni], acc[mi][ni]);
    __builtin_amdgcn_s_setprio(0);
    SBAR();
    h16* t;
    t = A0; A0 = A1; A1 = A2; A2 = t;
    t = B0; B0 = B1; B1 = B2; B2 = t;
  }

  #pragma unroll
  for (int ni = 0; ni < 4; ++ni) {
    int n = n0 + wn * 64 + ni * 16 + l15;
    #pragma unroll
    for (int mi = 0; mi < 8; ++mi) {
      #pragma unroll
      for (int r = 0; r < 4; ++r) {
        int m = m0 + wq * 128 + mi * 16 + g * 4 + r;
        y[(size_t)m * D_ + n] = (h16)(acc[mi][ni][r]);
      }
    }
  }
}

// -- kernel 5: scores block 256q x 256k = y·xh^T (+c_t), softmax partial -----
// 512 blocks (1/CU): b=blk&7 (XCD), r=blk>>3, kc=r>>3 (slow -> K L2 reuse),
// q-tile=r&7.  8 waves (2 wq x 4 wkc), per-wave 128q x 64k (acc[8][4]).
__global__ __launch_bounds__(512, 2) void k_attn(
    const h16* __restrict__ y, const h16* __restrict__ xh,
    const float* __restrict__ wv, const float* __restrict__ cv,
    float* __restrict__ part) {
  __shared__ alignas(16) h16 Qs[3][256 * 32];   // 48 KB
  __shared__ alignas(16) h16 Ks[3][256 * 32];   // 48 KB
  __shared__ float sm[3][4][256];               // 12 KB
  int tid = threadIdx.x;
  int w = tid >> 6, lane = tid & 63;
  int g = lane >> 4, l15 = lane & 15;
  int swz = (l15 >> 1) & 3;
  int wq = w >> 2, wkc = w & 3;                  // wave: 128q x 64k sub-tile
  int b = blockIdx.x & 7;
  int r = blockIdx.x >> 3;
  int kc = r >> 3;
  int q0 = (r & 7) * 256;
  size_t rbase = (size_t)b * S_;

  const h16* qbase0 = y + (rbase + q0 + (2 * w) * 16) * D_;
  const h16* qbase1 = qbase0 + (size_t)16 * D_;
  const h16* kbase0 = xh + (rbase + kc * 256 + (2 * w) * 16) * D_;
  const h16* kbase1 = kbase0 + (size_t)16 * D_;

  #define STAGE_ATTN(qp, kp, st)                             \
    {                                                        \
      int k0_ = (st) * 32;                                   \
      stage16(qbase0 + k0_, D_, (qp) + (2 * w) * 512);       \
      stage16(qbase1 + k0_, D_, (qp) + (2 * w + 1) * 512);   \
      stage16(kbase0 + k0_, D_, (kp) + (2 * w) * 512);       \
      stage16(kbase1 + k0_, D_, (kp) + (2 * w + 1) * 512);   \
    }

  f32x4 acc[8][4] = {};

  h16 *Q0 = Qs[0], *Q1 = Qs[1], *Q2 = Qs[2];
  h16 *K0 = Ks[0], *K1 = Ks[1], *K2 = Ks[2];
  STAGE_ATTN(Q0, K0, 0);
  STAGE_ATTN(Q1, K1, 1);
  for (int st = 0; st < 32; ++st) {
    if (st + 2 < 32) {
      STAGE_ATTN(Q2, K2, st + 2);
      VMCNT(8);
    } else if (st + 1 < 32) {
      VMCNT(4);
    } else {
      VMCNT(0);
    }
    SFENCE();
    SBAR();
    SFENCE();
    f16x8 qf[8], kf[4];
    #pragma unroll
    for (int i = 0; i < 8; ++i)
      qf[i] = *(const f16x8*)(Q0 + (wq * 128 + i * 16 + l15) * 32 + (g ^ swz) * 8);
    #pragma unroll
    for (int i = 0; i < 4; ++i)
      kf[i] = *(const f16x8*)(K0 + (wkc * 64 + i * 16 + l15) * 32 + (g ^ swz) * 8);
    __builtin_amdgcn_s_setprio(1);
    #pragma unroll
    for (int mi = 0; mi < 8; ++mi)
      #pragma unroll
      for (int ni = 0; ni < 4; ++ni)
        acc[mi][ni] = MFMA16(qf[mi], kf[ni], acc[mi][ni]);
    __builtin_amdgcn_s_setprio(0);
    SBAR();
    h16* t;
    t = Q0; Q0 = Q1; Q1 = Q2; Q2 = t;
    t = K0; K0 = K1; K1 = K2; K2 = t;
  }

  // ---- softmax partial over this block's 256 keys (scores + c_t) ----
  float wvv[4], cvv[4];
  #pragma unroll
  for (int ni = 0; ni < 4; ++ni) {
    size_t t = rbase + kc * 256 + wkc * 64 + ni * 16 + l15;
    wvv[ni] = wv[t];
    cvv[ni] = cv[t];
  }
  #pragma unroll
  for (int mi = 0; mi < 8; ++mi) {
    #pragma unroll
    for (int rr = 0; rr < 4; ++rr) {
      float s0 = acc[mi][0][rr] + cvv[0];
      float s1 = acc[mi][1][rr] + cvv[1];
      float s2 = acc[mi][2][rr] + cvv[2];
      float s3 = acc[mi][3][rr] + cvv[3];
      float v = fmaxf(fmaxf(s0, s1), fmaxf(s2, s3));
      #pragma unroll
      for (int off = 1; off < 16; off <<= 1) v = fmaxf(v, __shfl_xor(v, off, 64));
      float p0 = __expf(s0 - v), p1 = __expf(s1 - v);
      float p2 = __expf(s2 - v), p3 = __expf(s3 - v);
      float pn = p0 * wvv[0] + p1 * wvv[1] + p2 * wvv[2] + p3 * wvv[3];
      float pd = p0 + p1 + p2 + p3;
      #pragma unroll
      for (int off = 1; off < 16; off <<= 1) {
        pn += __shfl_xor(pn, off, 64);
        pd += __shfl_xor(pd, off, 64);
      }
      if (l15 == 0) {
        int row = wq * 128 + mi * 16 + g * 4 + rr;
        sm[0][wkc][row] = v;
        sm[1][wkc][row] = pn;
        sm[2][wkc][row] = pd;
      }
    }
  }
  __syncthreads();
  if (tid < 256) {
    float M = sm[0][0][tid];
    #pragma unroll
    for (int j = 1; j < 4; ++j) M = fmaxf(M, sm[0][j][tid]);
    float N = 0.f, Dn = 0.f;
    #pragma unroll
    for (int j = 0; j < 4; ++j) {
      float e = __expf(sm[0][j][tid] - M);
      N += sm[1][j][tid] * e;
      Dn += sm[2][j][tid] * e;
    }
    size_t row = rbase + q0 + tid;
    part[row * 24 + kc * 3 + 0] = M;
    part[row * 24 + kc * 3 + 1] = N;
    part[row * 24 + kc * 3 + 2] = Dn;
  }
}

// ------------- kernel 6: merge the 8 key-chunk partials ---------------------
__global__ void k_fin(const float* __restrict__ part, const float* __restrict__ bo,
                      float* __restrict__ out) {
  int idx = blockIdx.x * 256 + threadIdx.x;
  if (idx >= B_ * S_) return;
  const float* p = part + (size_t)idx * 24;
  float M = p[0];
  #pragma unroll
  for (int j = 1; j < 8; ++j) M = fmaxf(M, p[j * 3]);
  float N = 0.f, Dn = 0.f;
  #pragma unroll
  for (int j = 0; j < 8; ++j) {
    float e = __expf(p[j * 3] - M);
    N += p[j * 3 + 1] * e;
    Dn += p[j * 3 + 2] * e;
  }
  out[idx] = N / Dn + bo[0];
}

extern "C" void kernel_launch(void* const* d_in, const int* in_sizes, int n_in,
                              void* d_out, int out_size, void* d_ws, size_t ws_size,
                              hipStream_t stream) {
  const float* x  = (const float*)d_in[0];
  const float* Wq = (const float*)d_in[1];
  const float* bq = (const float*)d_in[2];
  const float* Wk = (const float*)d_in[3];
  const float* bk = (const float*)d_in[4];
  const float* Wv = (const float*)d_in[5];
  const float* bv = (const float*)d_in[6];
  const float* Wo = (const float*)d_in[7];
  const float* bo = (const float*)d_in[8];
  float* out = (float*)d_out;
  (void)bk;  // bq·bk and a_s terms cancel in softmax (row-constant)

  char* ws = (char*)d_ws;
  h16*   xh   = (h16*)ws;                                          // 32 MB
  h16*   yb   = (h16*)(ws + (size_t)32 * 1024 * 1024);             // 32 MB
  h16*   Mt   = (h16*)(ws + (size_t)64 * 1024 * 1024);             // 2 MB
  h16*   Wqh  = (h16*)(ws + (size_t)66 * 1024 * 1024);             // 2 MB
  h16*   Wkh  = (h16*)(ws + (size_t)68 * 1024 * 1024);             // 2 MB
  float* wv   = (float*)(ws + (size_t)70 * 1024 * 1024);           // 64 KB
  float* cv   = (float*)(ws + (size_t)70 * 1024 * 1024 + 65536);   // 64 KB
  float* u    = (float*)(ws + (size_t)70 * 1024 * 1024 + 131072);  // 4.1 KB
  float* v2   = (float*)(ws + (size_t)70 * 1024 * 1024 + 139264);  // 4 KB
  float* part = (float*)(ws + (size_t)71 * 1024 * 1024);           // 1.5 MB

  hipLaunchKernelGGL(k_cast, dim3(2048), dim3(256), 0, stream, Wq, Wk, Wqh, Wkh);
  hipLaunchKernelGGL(k_u,    dim3(257),  dim3(256), 0, stream, Wv, Wk, Wo, bq, bv, u, v2);
  hipLaunchKernelGGL(k_xw,   dim3(4096), dim3(256), 0, stream, x, u, v2, xh, wv, cv);
  hipLaunchKernelGGL(k_mt,   dim3(64),   dim3(256), 0, stream, Wkh, Wqh, Mt);
  hipLaunchKernelGGL(k_y,    dim3(256),  dim3(512), 0, stream, xh, Mt, yb);
  hipLaunchKernelGGL(k_attn, dim3(512),  dim3(512), 0, stream, yb, xh, wv, cv, part);
  hipLaunchKernelGGL(k_fin,  dim3(64),   dim3(256), 0, stream, part, bo, out);
}